// Round 6
// baseline (71.336 us; speedup 1.0000x reference)
//
#include <hip/hip_runtime.h>
#include <math.h>

#define B_TOTAL 8192
#define C_DIM 62
#define CC (C_DIM * C_DIM)   // 3844 floats
#define EPSV 1e-4f
#define NSWEEP 6
#define WSTRIDE 72           // per-group exchange stride

// ---------------- Kernel A: M1[b] = w1^T X[b] w1  (62->8) ----------------
// One wave per batch. X staged via global_load_lds (linear dest), Y per-row.
__global__ __launch_bounds__(64) void bimap1_kernel(
    const float* __restrict__ X, const float* __restrict__ w1,
    float* __restrict__ M1) {
  __shared__ __align__(16) float Xs[3856];       // 3844 used
  __shared__ __align__(16) float w1s[C_DIM * 8]; // 496
  __shared__ __align__(16) float Ys[C_DIM * 8];  // 496
  const int lane = threadIdx.x;
  const int b = blockIdx.x;
  const float* Xb = X + (size_t)b * CC;

  // 15 full-wave async chunks: 15 * 64 lanes * 16B = 15360B of 15376B
#pragma unroll
  for (int ch = 0; ch < 15; ++ch) {
    const float* src = Xb + ch * 256 + lane * 4;
    __builtin_amdgcn_global_load_lds(
        (const __attribute__((address_space(1))) unsigned int*)src,
        (__attribute__((address_space(3))) unsigned int*)(Xs + ch * 256),
        16, 0, 0);
  }
  // tail chunk (floats 3840..3843)
  if (lane == 0) *(float4*)(Xs + 3840) = *(const float4*)(Xb + 3840);
  // w1 row c (8 floats, 32B-aligned rows)
  if (lane < C_DIM) {
    *(float4*)(w1s + lane * 8)     = *(const float4*)(w1 + lane * 8);
    *(float4*)(w1s + lane * 8 + 4) = *(const float4*)(w1 + lane * 8 + 4);
  }
  __syncthreads();

  // Y[c][e] = sum_d X[c][d] * w1[d][e] ; lane c owns row c
  if (lane < C_DIM) {
    float a0=0.f,a1=0.f,a2=0.f,a3=0.f,a4=0.f,a5=0.f,a6=0.f,a7=0.f;
#pragma unroll
    for (int dp = 0; dp < 31; ++dp) {
      float2 x2 = *(const float2*)(Xs + lane * C_DIM + dp * 2); // 8B-aligned
      float4 wA0 = *(const float4*)(w1s + dp * 16);       // row 2dp   e=0..3
      float4 wB0 = *(const float4*)(w1s + dp * 16 + 4);   // row 2dp   e=4..7
      float4 wA1 = *(const float4*)(w1s + dp * 16 + 8);   // row 2dp+1 e=0..3
      float4 wB1 = *(const float4*)(w1s + dp * 16 + 12);  // row 2dp+1 e=4..7
      a0 = fmaf(x2.x, wA0.x, a0); a1 = fmaf(x2.x, wA0.y, a1);
      a2 = fmaf(x2.x, wA0.z, a2); a3 = fmaf(x2.x, wA0.w, a3);
      a4 = fmaf(x2.x, wB0.x, a4); a5 = fmaf(x2.x, wB0.y, a5);
      a6 = fmaf(x2.x, wB0.z, a6); a7 = fmaf(x2.x, wB0.w, a7);
      a0 = fmaf(x2.y, wA1.x, a0); a1 = fmaf(x2.y, wA1.y, a1);
      a2 = fmaf(x2.y, wA1.z, a2); a3 = fmaf(x2.y, wA1.w, a3);
      a4 = fmaf(x2.y, wB1.x, a4); a5 = fmaf(x2.y, wB1.y, a5);
      a6 = fmaf(x2.y, wB1.z, a6); a7 = fmaf(x2.y, wB1.w, a7);
    }
    *(float4*)(Ys + lane * 8)     = make_float4(a0, a1, a2, a3);
    *(float4*)(Ys + lane * 8 + 4) = make_float4(a4, a5, a6, a7);
  }
  __syncthreads();

  // M1[a][e] = sum_c w1[c][a] * Y[c][e] ; lane = (a<<3)|e
  {
    const int a = lane >> 3, e = lane & 7;
    float s = 0.f;
#pragma unroll
    for (int c = 0; c < C_DIM; ++c)
      s = fmaf(w1s[c * 8 + a], Ys[c * 8 + e], s);
    M1[(size_t)b * 64 + lane] = s;
  }
}

// ---------- cross-lane xor-shuffle: DPP (VALU) for masks 1..3, swizzle else ----------
template<int M> __device__ __forceinline__ float sx(float x) {
  int xi = __builtin_bit_cast(int, x);
  int r;
  if constexpr (M == 1)      r = __builtin_amdgcn_update_dpp(xi, xi, 0xB1, 0xF, 0xF, false);
  else if constexpr (M == 2) r = __builtin_amdgcn_update_dpp(xi, xi, 0x4E, 0xF, 0xF, false);
  else if constexpr (M == 3) r = __builtin_amdgcn_update_dpp(xi, xi, 0x1B, 0xF, 0xF, false);
  else                       r = __builtin_amdgcn_ds_swizzle(xi, (M << 10) | 0x1F);
  return __builtin_bit_cast(float, r);
}

// in-register xor-permute: r[j] <- r[j ^ e]   (24 cndmask)
__device__ __forceinline__ void xperm8(float r[8], const int e) {
  const bool b0 = (e & 1) != 0, b1 = (e & 2) != 0, b2 = (e & 4) != 0;
  float t0[8], t1[8];
#pragma unroll
  for (int j = 0; j < 8; ++j) t0[j] = b0 ? r[j ^ 1] : r[j];
#pragma unroll
  for (int j = 0; j < 8; ++j) t1[j] = b1 ? t0[j ^ 2] : t0[j];
#pragma unroll
  for (int j = 0; j < 8; ++j) r[j] = b2 ? t1[j ^ 4] : t1[j];
}

// ---------- one tournament stage, XOR-relative storage ----------
// lane e stores ar[d] = A[e^d][e], ur[d] = U[e^d][e]. Pairs (i, i^M).
template<int M>
__device__ __forceinline__ void jstage(float ar[8], float ur[8], const int e) {
  constexpr int HB = (M >= 4) ? 4 : ((M >= 2) ? 2 : 1);  // highest bit of M
  constexpr int A1 = (M == 1) ? 2 : 1;                   // transversal masks
  constexpr int A2 = (M <= 3) ? 4 : 2;
  const bool low = (e & HB) == 0;      // is e the min of its pair
  // own diag = ar[0], own off-diag = ar[M] (both static!)
  float d_oth = sx<M>(ar[0]);
  float o_oth = sx<M>(ar[M]);
  float apq = 0.5f * (ar[M] + o_oth);  // symmetrized: both lanes identical
  float app = low ? ar[0] : d_oth;
  float aqq = low ? d_oth : ar[0];
  float taun = aqq - app;
  float den = fabsf(taun) + sqrtf(fmaf(taun, taun, 4.f * apq * apq)) + 1e-38f;
  float t = (2.f * apq) * copysignf(1.f, taun) * __builtin_amdgcn_rcpf(den);
  float c = rsqrtf(fmaf(t, t, 1.f));
  float s = t * c;                      // canonical (p=min, q=max) rotation
  // allgather canonical (c,s) of all 4 pairs into transversal slots (static idx)
  float cg[8], sg[8];
  cg[0] = c;  sg[0] = s;
  cg[A1] = sx<A1>(c);  sg[A1] = sx<A1>(s);
  cg[A2] = sx<A2>(c);  sg[A2] = sx<A2>(s);
  cg[A1 ^ A2] = sx<A2>(cg[A1]);  sg[A1 ^ A2] = sx<A2>(sg[A1]);
  // row update: A <- J^T A   (rel pair {d, d^M} uses slot rep(d))
  float an[8];
#pragma unroll
  for (int d = 0; d < 8; ++d) {
    constexpr int T0 = 0;
    const int rep = (d == T0 || d == A1 || d == A2 || d == (A1 ^ A2)) ? d : (d ^ M);
    const bool flip = (d & HB) != 0;       // abs row e^d is low iff low^flip
    float sD = sg[rep];
    float ss = (low != flip) ? -sD : sD;   // row_p gets -s, row_q gets +s
    an[d] = fmaf(cg[rep], ar[d], ss * ar[d ^ M]);
  }
  // col update: A <- A J ; U <- U J  (own pair's rotation; partner col via shfl)
  float scol = low ? -s : s;
  float aoth[8], uoth[8];
#pragma unroll
  for (int d = 0; d < 8; ++d) aoth[d] = sx<M>(an[d ^ M]);
#pragma unroll
  for (int d = 0; d < 8; ++d) uoth[d] = sx<M>(ur[d ^ M]);
#pragma unroll
  for (int d = 0; d < 8; ++d) ar[d] = fmaf(c, an[d], scol * aoth[d]);
#pragma unroll
  for (int d = 0; d < 8; ++d) ur[d] = fmaf(c, ur[d], scol * uoth[d]);
}

__device__ __forceinline__ void jacobi8rel(float ar[8], float ur[8], const int e) {
#pragma unroll
  for (int i = 0; i < 8; ++i) ur[i] = (i == 0) ? 1.f : 0.f;  // identity (relative)
#pragma unroll 1
  for (int sweep = 0; sweep < NSWEEP; ++sweep) {
    jstage<1>(ar, ur, e);
    jstage<2>(ar, ur, e);
    jstage<3>(ar, ur, e);
    jstage<4>(ar, ur, e);
    jstage<5>(ar, ur, e);
    jstage<6>(ar, ur, e);
    jstage<7>(ar, ur, e);
  }
}

// ---------------- Kernel B: eig pipeline, 1 wave = 8 batches ----------------
__global__ __launch_bounds__(64) void spd_eig8_kernel(
    const float* __restrict__ M1, const float* __restrict__ w2,
    const float* __restrict__ fc, float* __restrict__ out) {
  __shared__ __align__(16) float Wbuf[8 * WSTRIDE];
  __shared__ float lwbuf[64];
  __shared__ float w2s[64];
  __shared__ float fcs[128];
  const int tid = threadIdx.x;      // 0..63
  const int e = tid & 7;
  const int g = tid >> 3;           // 0..7, batch group
  const int b = blockIdx.x * 8 + g;
  w2s[tid] = w2[tid];
  fcs[tid] = fc[tid];
  fcs[tid + 64] = fc[tid + 64];

  float a[8], u[8], v[8], m2[8];
  float* Wg = &Wbuf[g * WSTRIDE];

  // load row e of symmetric M1 (= column e); coalesced 2KB per block
  const float4* m4 = (const float4*)(M1 + (size_t)b * 64 + e * 8);
  float4 v0 = m4[0], v1 = m4[1];
  a[0] = v0.x; a[1] = v0.y; a[2] = v0.z; a[3] = v0.w;
  a[4] = v1.x; a[5] = v1.y; a[6] = v1.z; a[7] = v1.w;
  __syncthreads();  // w2s/fcs ready (intra-wave: cheap)

  // ---- eig 1 ----
  xperm8(a, e);                 // absolute row -> relative column
  jacobi8rel(a, u, e);
  float lam = a[0];             // own eigenvalue (rel slot 0)
  float sw = sqrtf(fmaxf(lam, EPSV));
  xperm8(u, e);                 // u[i] = U[i][e] absolute
  // row e of V = U^T w2, scaled by sqrt(clamped eig)
#pragma unroll
  for (int j = 0; j < 8; ++j) v[j] = 0.f;
#pragma unroll
  for (int i = 0; i < 8; ++i)
#pragma unroll
    for (int j = 0; j < 8; ++j) v[j] = fmaf(u[i], w2s[i * 8 + j], v[j]);
#pragma unroll
  for (int j = 0; j < 8; ++j) Wg[e * 8 + j] = v[j] * sw;
  __syncthreads();
  // M2 column e: m2[i] = sum_k W[k][i] * W[k][e]
  {
    float wcol[8];
#pragma unroll
    for (int k = 0; k < 8; ++k) wcol[k] = Wg[k * 8 + e];
#pragma unroll
    for (int i = 0; i < 8; ++i) m2[i] = 0.f;
#pragma unroll
    for (int k = 0; k < 8; ++k) {
      float4 q0 = *(const float4*)&Wg[k * 8 + 0];
      float4 q1 = *(const float4*)&Wg[k * 8 + 4];
      m2[0] = fmaf(q0.x, wcol[k], m2[0]); m2[1] = fmaf(q0.y, wcol[k], m2[1]);
      m2[2] = fmaf(q0.z, wcol[k], m2[2]); m2[3] = fmaf(q0.w, wcol[k], m2[3]);
      m2[4] = fmaf(q1.x, wcol[k], m2[4]); m2[5] = fmaf(q1.y, wcol[k], m2[5]);
      m2[6] = fmaf(q1.z, wcol[k], m2[6]); m2[7] = fmaf(q1.w, wcol[k], m2[7]);
    }
  }
  __syncthreads();  // Wbuf reads done before reuse

  // ---- eig 2 + fused rec+logm ----
  xperm8(m2, e);
  jacobi8rel(m2, u, e);
  float lw = logf(fmaxf(m2[0], EPSV));
  xperm8(u, e);                 // absolute again
#pragma unroll
  for (int i = 0; i < 8; ++i) Wg[e * 8 + i] = u[i];
  lwbuf[g * 8 + e] = lw;
  __syncthreads();
  // feat column e: fcol[i] = sum_k lw_k * T[k][i] * T[k][e]
  {
    float mk[8];
#pragma unroll
    for (int k = 0; k < 8; ++k) mk[k] = lwbuf[g * 8 + k] * Wg[k * 8 + e];
    float fcol[8];
#pragma unroll
    for (int i = 0; i < 8; ++i) fcol[i] = 0.f;
#pragma unroll
    for (int k = 0; k < 8; ++k) {
      float4 q0 = *(const float4*)&Wg[k * 8 + 0];
      float4 q1 = *(const float4*)&Wg[k * 8 + 4];
      fcol[0] = fmaf(q0.x, mk[k], fcol[0]); fcol[1] = fmaf(q0.y, mk[k], fcol[1]);
      fcol[2] = fmaf(q0.z, mk[k], fcol[2]); fcol[3] = fmaf(q0.w, mk[k], fcol[3]);
      fcol[4] = fmaf(q1.x, mk[k], fcol[4]); fcol[5] = fmaf(q1.y, mk[k], fcol[5]);
      fcol[6] = fmaf(q1.z, mk[k], fcol[6]); fcol[7] = fmaf(q1.w, mk[k], fcol[7]);
    }
    float l0 = 0.f, l1 = 0.f;
    float* featg = out + 2 * (size_t)B_TOTAL + (size_t)b * 64;
#pragma unroll
    for (int i = 0; i < 8; ++i) {
      featg[i * 8 + e] = fcol[i];
      l0 = fmaf(fcol[i], fcs[(i * 8 + e) * 2 + 0], l0);
      l1 = fmaf(fcol[i], fcs[(i * 8 + e) * 2 + 1], l1);
    }
    l0 += sx<1>(l0); l0 += sx<2>(l0); l0 += sx<4>(l0);
    l1 += sx<1>(l1); l1 += sx<2>(l1); l1 += sx<4>(l1);
    float mx = fmaxf(l0, l1);
    float lse = mx + logf(expf(l0 - mx) + expf(l1 - mx));
    if (e < 2) out[(size_t)b * 2 + e] = (e ? l1 : l0) - lse;
  }
}

extern "C" void kernel_launch(void* const* d_in, const int* in_sizes, int n_in,
                              void* d_out, int out_size, void* d_ws, size_t ws_size,
                              hipStream_t stream) {
  const float* X  = (const float*)d_in[0];   // [8192,62,62]
  const float* w1 = (const float*)d_in[1];   // [62,8]
  const float* w2 = (const float*)d_in[2];   // [8,8]
  const float* fc = (const float*)d_in[3];   // [64,2]
  float* out = (float*)d_out;                // [8192*2] ++ [8192*64]
  float* M1 = (float*)d_ws;                  // 8192*64 floats = 2 MB

  bimap1_kernel<<<B_TOTAL, 64, 0, stream>>>(X, w1, M1);
  spd_eig8_kernel<<<B_TOTAL / 8, 64, 0, stream>>>(M1, w2, fc, out);
}

// Round 7
// 70.153 us; speedup vs baseline: 1.0169x; 1.0169x over previous
//
#include <hip/hip_runtime.h>
#include <math.h>

#define B_TOTAL 8192
#define C_DIM 62
#define CC (C_DIM * C_DIM)   // 3844 floats
#define EPSV 1e-4f
#define NSWEEP 6
#define WSTRIDE 72           // per-group exchange stride
#define YSTR 9               // Ys stride: gcd(9,32)=1 -> conflict-free writes

// ---------------- Kernel A: M1[b] = w1^T X[b] w1  (62->8) ----------------
// One wave per batch. X staged via global_load_lds; w1 read via SCALAR loads
// (wave-uniform compile-time offsets -> s_load, off the LDS pipe entirely).
__global__ __launch_bounds__(64) void bimap1_kernel(
    const float* __restrict__ X, const float* __restrict__ w1,
    float* __restrict__ M1) {
  __shared__ __align__(16) float Xs[3856];        // 3844 used
  __shared__ __align__(16) float w1s[C_DIM * 8];  // for M1 phase broadcasts
  __shared__ float Ys[C_DIM * YSTR];              // padded stride 9
  const int lane = threadIdx.x;
  const int b = blockIdx.x;
  const float* Xb = X + (size_t)b * CC;

  // 15 full-wave async chunks: 15 * 64 lanes * 16B = 15360B of 15376B
#pragma unroll
  for (int ch = 0; ch < 15; ++ch) {
    const float* src = Xb + ch * 256 + lane * 4;
    __builtin_amdgcn_global_load_lds(
        (const __attribute__((address_space(1))) unsigned int*)src,
        (__attribute__((address_space(3))) unsigned int*)(Xs + ch * 256),
        16, 0, 0);
  }
  // tail chunk (floats 3840..3843)
  if (lane == 0) *(float4*)(Xs + 3840) = *(const float4*)(Xb + 3840);
  // w1 -> LDS (only used by the M1 phase)
  if (lane < C_DIM) {
    *(float4*)(w1s + lane * 8)     = *(const float4*)(w1 + lane * 8);
    *(float4*)(w1s + lane * 8 + 4) = *(const float4*)(w1 + lane * 8 + 4);
  }
  __syncthreads();

  // Y[c][e] = sum_d X[c][d] * w1[d][e] ; lane c owns row c.
  // X row via 31 x ds_read_b64; w1 via scalar loads (uniform index).
  if (lane < C_DIM) {
    float a0=0.f,a1=0.f,a2=0.f,a3=0.f,a4=0.f,a5=0.f,a6=0.f,a7=0.f;
#pragma unroll
    for (int k = 0; k < 31; ++k) {
      float2 x2 = *(const float2*)(Xs + lane * C_DIM + 2 * k); // 8B-aligned
      const float* wr0 = w1 + (2 * k) * 8;      // wave-uniform -> s_load
      const float* wr1 = w1 + (2 * k + 1) * 8;
      a0 = fmaf(x2.x, wr0[0], a0); a1 = fmaf(x2.x, wr0[1], a1);
      a2 = fmaf(x2.x, wr0[2], a2); a3 = fmaf(x2.x, wr0[3], a3);
      a4 = fmaf(x2.x, wr0[4], a4); a5 = fmaf(x2.x, wr0[5], a5);
      a6 = fmaf(x2.x, wr0[6], a6); a7 = fmaf(x2.x, wr0[7], a7);
      a0 = fmaf(x2.y, wr1[0], a0); a1 = fmaf(x2.y, wr1[1], a1);
      a2 = fmaf(x2.y, wr1[2], a2); a3 = fmaf(x2.y, wr1[3], a3);
      a4 = fmaf(x2.y, wr1[4], a4); a5 = fmaf(x2.y, wr1[5], a5);
      a6 = fmaf(x2.y, wr1[6], a6); a7 = fmaf(x2.y, wr1[7], a7);
    }
    // padded scalar writes: bank = (9c+e) mod 32, conflict-free
    float* yr = Ys + lane * YSTR;
    yr[0]=a0; yr[1]=a1; yr[2]=a2; yr[3]=a3;
    yr[4]=a4; yr[5]=a5; yr[6]=a6; yr[7]=a7;
  }
  __syncthreads();

  // M1[a][e] = sum_c w1[c][a] * Y[c][e] ; lane = (a<<3)|e
  // both reads broadcast-grouped (8 lanes share each address) -> conflict-free
  {
    const int a = lane >> 3, e = lane & 7;
    float s = 0.f;
#pragma unroll
    for (int c = 0; c < C_DIM; ++c)
      s = fmaf(w1s[c * 8 + a], Ys[c * YSTR + e], s);
    M1[(size_t)b * 64 + lane] = s;
  }
}

// ---------- cross-lane xor-shuffle: DPP (VALU) for masks 1..3, swizzle else ----------
template<int M> __device__ __forceinline__ float sx(float x) {
  int xi = __builtin_bit_cast(int, x);
  int r;
  if constexpr (M == 1)      r = __builtin_amdgcn_update_dpp(xi, xi, 0xB1, 0xF, 0xF, false);
  else if constexpr (M == 2) r = __builtin_amdgcn_update_dpp(xi, xi, 0x4E, 0xF, 0xF, false);
  else if constexpr (M == 3) r = __builtin_amdgcn_update_dpp(xi, xi, 0x1B, 0xF, 0xF, false);
  else                       r = __builtin_amdgcn_ds_swizzle(xi, (M << 10) | 0x1F);
  return __builtin_bit_cast(float, r);
}

// in-register xor-permute: r[j] <- r[j ^ e]   (24 cndmask)
__device__ __forceinline__ void xperm8(float r[8], const int e) {
  const bool b0 = (e & 1) != 0, b1 = (e & 2) != 0, b2 = (e & 4) != 0;
  float t0[8], t1[8];
#pragma unroll
  for (int j = 0; j < 8; ++j) t0[j] = b0 ? r[j ^ 1] : r[j];
#pragma unroll
  for (int j = 0; j < 8; ++j) t1[j] = b1 ? t0[j ^ 2] : t0[j];
#pragma unroll
  for (int j = 0; j < 8; ++j) r[j] = b2 ? t1[j ^ 4] : t1[j];
}

// ---------- one tournament stage, XOR-relative storage ----------
// lane e stores ar[d] = A[e^d][e], ur[d] = U[e^d][e]. Pairs (i, i^M).
template<int M>
__device__ __forceinline__ void jstage(float ar[8], float ur[8], const int e) {
  constexpr int HB = (M >= 4) ? 4 : ((M >= 2) ? 2 : 1);  // highest bit of M
  constexpr int A1 = (M == 1) ? 2 : 1;                   // transversal masks
  constexpr int A2 = (M <= 3) ? 4 : 2;
  const bool low = (e & HB) == 0;      // is e the min of its pair
  // own diag = ar[0], own off-diag = ar[M] (both static!)
  float d_oth = sx<M>(ar[0]);
  float o_oth = sx<M>(ar[M]);
  float apq = 0.5f * (ar[M] + o_oth);  // symmetrized: both lanes identical
  float app = low ? ar[0] : d_oth;
  float aqq = low ? d_oth : ar[0];
  float taun = aqq - app;
  float den = fabsf(taun) + sqrtf(fmaf(taun, taun, 4.f * apq * apq)) + 1e-38f;
  float t = (2.f * apq) * copysignf(1.f, taun) * __builtin_amdgcn_rcpf(den);
  float c = rsqrtf(fmaf(t, t, 1.f));
  float s = t * c;                      // canonical (p=min, q=max) rotation
  // allgather canonical (c,s) of all 4 pairs into transversal slots (static idx)
  float cg[8], sg[8];
  cg[0] = c;  sg[0] = s;
  cg[A1] = sx<A1>(c);  sg[A1] = sx<A1>(s);
  cg[A2] = sx<A2>(c);  sg[A2] = sx<A2>(s);
  cg[A1 ^ A2] = sx<A2>(cg[A1]);  sg[A1 ^ A2] = sx<A2>(sg[A1]);
  // row update: A <- J^T A   (rel pair {d, d^M} uses slot rep(d))
  float an[8];
#pragma unroll
  for (int d = 0; d < 8; ++d) {
    constexpr int T0 = 0;
    const int rep = (d == T0 || d == A1 || d == A2 || d == (A1 ^ A2)) ? d : (d ^ M);
    const bool flip = (d & HB) != 0;       // abs row e^d is low iff low^flip
    float sD = sg[rep];
    float ss = (low != flip) ? -sD : sD;   // row_p gets -s, row_q gets +s
    an[d] = fmaf(cg[rep], ar[d], ss * ar[d ^ M]);
  }
  // col update: A <- A J ; U <- U J  (own pair's rotation; partner col via shfl)
  float scol = low ? -s : s;
  float aoth[8], uoth[8];
#pragma unroll
  for (int d = 0; d < 8; ++d) aoth[d] = sx<M>(an[d ^ M]);
#pragma unroll
  for (int d = 0; d < 8; ++d) uoth[d] = sx<M>(ur[d ^ M]);
#pragma unroll
  for (int d = 0; d < 8; ++d) ar[d] = fmaf(c, an[d], scol * aoth[d]);
#pragma unroll
  for (int d = 0; d < 8; ++d) ur[d] = fmaf(c, ur[d], scol * uoth[d]);
}

__device__ __forceinline__ void jacobi8rel(float ar[8], float ur[8], const int e) {
#pragma unroll
  for (int i = 0; i < 8; ++i) ur[i] = (i == 0) ? 1.f : 0.f;  // identity (relative)
#pragma unroll 1
  for (int sweep = 0; sweep < NSWEEP; ++sweep) {
    jstage<1>(ar, ur, e);
    jstage<2>(ar, ur, e);
    jstage<3>(ar, ur, e);
    jstage<4>(ar, ur, e);
    jstage<5>(ar, ur, e);
    jstage<6>(ar, ur, e);
    jstage<7>(ar, ur, e);
  }
}

// ---------------- Kernel B: eig pipeline, 1 wave = 8 batches ----------------
__global__ __launch_bounds__(64) void spd_eig8_kernel(
    const float* __restrict__ M1, const float* __restrict__ w2,
    const float* __restrict__ fc, float* __restrict__ out) {
  __shared__ __align__(16) float Wbuf[8 * WSTRIDE];
  __shared__ float lwbuf[64];
  __shared__ float w2s[64];
  __shared__ float fcs[128];
  const int tid = threadIdx.x;      // 0..63
  const int e = tid & 7;
  const int g = tid >> 3;           // 0..7, batch group
  const int b = blockIdx.x * 8 + g;
  w2s[tid] = w2[tid];
  fcs[tid] = fc[tid];
  fcs[tid + 64] = fc[tid + 64];

  float a[8], u[8], v[8], m2[8];
  float* Wg = &Wbuf[g * WSTRIDE];

  // load row e of symmetric M1 (= column e); coalesced 2KB per block
  const float4* m4 = (const float4*)(M1 + (size_t)b * 64 + e * 8);
  float4 v0 = m4[0], v1 = m4[1];
  a[0] = v0.x; a[1] = v0.y; a[2] = v0.z; a[3] = v0.w;
  a[4] = v1.x; a[5] = v1.y; a[6] = v1.z; a[7] = v1.w;
  __syncthreads();  // w2s/fcs ready (intra-wave: cheap)

  // ---- eig 1 ----
  xperm8(a, e);                 // absolute row -> relative column
  jacobi8rel(a, u, e);
  float lam = a[0];             // own eigenvalue (rel slot 0)
  float sw = sqrtf(fmaxf(lam, EPSV));
  xperm8(u, e);                 // u[i] = U[i][e] absolute
  // row e of V = U^T w2, scaled by sqrt(clamped eig)
#pragma unroll
  for (int j = 0; j < 8; ++j) v[j] = 0.f;
#pragma unroll
  for (int i = 0; i < 8; ++i)
#pragma unroll
    for (int j = 0; j < 8; ++j) v[j] = fmaf(u[i], w2s[i * 8 + j], v[j]);
#pragma unroll
  for (int j = 0; j < 8; ++j) Wg[e * 8 + j] = v[j] * sw;
  __syncthreads();
  // M2 column e: m2[i] = sum_k W[k][i] * W[k][e]
  {
    float wcol[8];
#pragma unroll
    for (int k = 0; k < 8; ++k) wcol[k] = Wg[k * 8 + e];
#pragma unroll
    for (int i = 0; i < 8; ++i) m2[i] = 0.f;
#pragma unroll
    for (int k = 0; k < 8; ++k) {
      float4 q0 = *(const float4*)&Wg[k * 8 + 0];
      float4 q1 = *(const float4*)&Wg[k * 8 + 4];
      m2[0] = fmaf(q0.x, wcol[k], m2[0]); m2[1] = fmaf(q0.y, wcol[k], m2[1]);
      m2[2] = fmaf(q0.z, wcol[k], m2[2]); m2[3] = fmaf(q0.w, wcol[k], m2[3]);
      m2[4] = fmaf(q1.x, wcol[k], m2[4]); m2[5] = fmaf(q1.y, wcol[k], m2[5]);
      m2[6] = fmaf(q1.z, wcol[k], m2[6]); m2[7] = fmaf(q1.w, wcol[k], m2[7]);
    }
  }
  __syncthreads();  // Wbuf reads done before reuse

  // ---- eig 2 + fused rec+logm ----
  xperm8(m2, e);
  jacobi8rel(m2, u, e);
  float lw = logf(fmaxf(m2[0], EPSV));
  xperm8(u, e);                 // absolute again
#pragma unroll
  for (int i = 0; i < 8; ++i) Wg[e * 8 + i] = u[i];
  lwbuf[g * 8 + e] = lw;
  __syncthreads();
  // feat column e: fcol[i] = sum_k lw_k * T[k][i] * T[k][e]
  {
    float mk[8];
#pragma unroll
    for (int k = 0; k < 8; ++k) mk[k] = lwbuf[g * 8 + k] * Wg[k * 8 + e];
    float fcol[8];
#pragma unroll
    for (int i = 0; i < 8; ++i) fcol[i] = 0.f;
#pragma unroll
    for (int k = 0; k < 8; ++k) {
      float4 q0 = *(const float4*)&Wg[k * 8 + 0];
      float4 q1 = *(const float4*)&Wg[k * 8 + 4];
      fcol[0] = fmaf(q0.x, mk[k], fcol[0]); fcol[1] = fmaf(q0.y, mk[k], fcol[1]);
      fcol[2] = fmaf(q0.z, mk[k], fcol[2]); fcol[3] = fmaf(q0.w, mk[k], fcol[3]);
      fcol[4] = fmaf(q1.x, mk[k], fcol[4]); fcol[5] = fmaf(q1.y, mk[k], fcol[5]);
      fcol[6] = fmaf(q1.z, mk[k], fcol[6]); fcol[7] = fmaf(q1.w, mk[k], fcol[7]);
    }
    float l0 = 0.f, l1 = 0.f;
    float* featg = out + 2 * (size_t)B_TOTAL + (size_t)b * 64;
#pragma unroll
    for (int i = 0; i < 8; ++i) {
      featg[i * 8 + e] = fcol[i];
      l0 = fmaf(fcol[i], fcs[(i * 8 + e) * 2 + 0], l0);
      l1 = fmaf(fcol[i], fcs[(i * 8 + e) * 2 + 1], l1);
    }
    l0 += sx<1>(l0); l0 += sx<2>(l0); l0 += sx<4>(l0);
    l1 += sx<1>(l1); l1 += sx<2>(l1); l1 += sx<4>(l1);
    float mx = fmaxf(l0, l1);
    float lse = mx + logf(expf(l0 - mx) + expf(l1 - mx));
    if (e < 2) out[(size_t)b * 2 + e] = (e ? l1 : l0) - lse;
  }
}

extern "C" void kernel_launch(void* const* d_in, const int* in_sizes, int n_in,
                              void* d_out, int out_size, void* d_ws, size_t ws_size,
                              hipStream_t stream) {
  const float* X  = (const float*)d_in[0];   // [8192,62,62]
  const float* w1 = (const float*)d_in[1];   // [62,8]
  const float* w2 = (const float*)d_in[2];   // [8,8]
  const float* fc = (const float*)d_in[3];   // [64,2]
  float* out = (float*)d_out;                // [8192*2] ++ [8192*64]
  float* M1 = (float*)d_ws;                  // 8192*64 floats = 2 MB

  bimap1_kernel<<<B_TOTAL, 64, 0, stream>>>(X, w1, M1);
  spd_eig8_kernel<<<B_TOTAL / 8, 64, 0, stream>>>(M1, w2, fc, out);
}

// Round 8
// 67.557 us; speedup vs baseline: 1.0559x; 1.0384x over previous
//
#include <hip/hip_runtime.h>
#include <math.h>

#define B_TOTAL 8192
#define C_DIM 62
#define CC (C_DIM * C_DIM)   // 3844 floats
#define EPSV 1e-4f
#define NSWEEP 6
#define WSTRIDE 72           // per-group exchange stride
#define YSTR 9               // Ys stride: gcd(9,32)=1 -> conflict-free writes

// ---------------- Kernel A: M1[b] = w1^T X[b] w1  (62->8) ----------------
// One wave per batch. NO X staging: lane c reads row c of X straight into
// registers (rows are 8B-aligned; every cache line fully consumed). LDS is
// only w1 (uniform broadcast reads) + Ys exchange -> ~4.3 KB -> high occupancy.
__global__ __launch_bounds__(64, 4) void bimap1_kernel(
    const float* __restrict__ X, const float* __restrict__ w1,
    float* __restrict__ M1) {
  __shared__ __align__(16) float w1s[C_DIM * 8];  // 496
  __shared__ float Ys[C_DIM * YSTR];              // padded stride 9
  const int lane = threadIdx.x;
  const int b = blockIdx.x;

  // my X row -> 62 registers (31 x float2, always 8B-aligned: 248*c % 8 == 0)
  float xr[C_DIM];
  {
    const float* row = X + (size_t)b * CC + lane * C_DIM;
    if (lane < C_DIM) {
#pragma unroll
      for (int k = 0; k < 31; ++k) {
        float2 t = *(const float2*)(row + 2 * k);
        xr[2 * k] = t.x;
        xr[2 * k + 1] = t.y;
      }
    }
  }
  // w1 -> LDS (32B-aligned rows)
  if (lane < C_DIM) {
    *(float4*)(w1s + lane * 8)     = *(const float4*)(w1 + lane * 8);
    *(float4*)(w1s + lane * 8 + 4) = *(const float4*)(w1 + lane * 8 + 4);
  }
  __syncthreads();

  // Y[c][e] = sum_d X[c][d] * w1[d][e] ; lane c owns row c.
  // w1s reads are wave-uniform -> LDS broadcast, conflict-free.
  if (lane < C_DIM) {
    float a0=0.f,a1=0.f,a2=0.f,a3=0.f,a4=0.f,a5=0.f,a6=0.f,a7=0.f;
#pragma unroll
    for (int d = 0; d < C_DIM; ++d) {
      float x = xr[d];
      float4 wA = *(const float4*)(w1s + d * 8);
      float4 wB = *(const float4*)(w1s + d * 8 + 4);
      a0 = fmaf(x, wA.x, a0); a1 = fmaf(x, wA.y, a1);
      a2 = fmaf(x, wA.z, a2); a3 = fmaf(x, wA.w, a3);
      a4 = fmaf(x, wB.x, a4); a5 = fmaf(x, wB.y, a5);
      a6 = fmaf(x, wB.z, a6); a7 = fmaf(x, wB.w, a7);
    }
    // padded scalar writes: bank = (9c+e) mod 32, conflict-free
    float* yr = Ys + lane * YSTR;
    yr[0]=a0; yr[1]=a1; yr[2]=a2; yr[3]=a3;
    yr[4]=a4; yr[5]=a5; yr[6]=a6; yr[7]=a7;
  }
  __syncthreads();

  // M1[a][e] = sum_c w1[c][a] * Y[c][e] ; lane = (a<<3)|e
  // both reads broadcast-grouped (8 lanes share each address) -> conflict-free
  {
    const int a = lane >> 3, e = lane & 7;
    float s = 0.f;
#pragma unroll
    for (int c = 0; c < C_DIM; ++c)
      s = fmaf(w1s[c * 8 + a], Ys[c * YSTR + e], s);
    M1[(size_t)b * 64 + lane] = s;
  }
}

// ---------- cross-lane xor-shuffle: DPP (VALU) for masks 1..3, swizzle else ----------
template<int M> __device__ __forceinline__ float sx(float x) {
  int xi = __builtin_bit_cast(int, x);
  int r;
  if constexpr (M == 1)      r = __builtin_amdgcn_update_dpp(xi, xi, 0xB1, 0xF, 0xF, false);
  else if constexpr (M == 2) r = __builtin_amdgcn_update_dpp(xi, xi, 0x4E, 0xF, 0xF, false);
  else if constexpr (M == 3) r = __builtin_amdgcn_update_dpp(xi, xi, 0x1B, 0xF, 0xF, false);
  else                       r = __builtin_amdgcn_ds_swizzle(xi, (M << 10) | 0x1F);
  return __builtin_bit_cast(float, r);
}

// in-register xor-permute: r[j] <- r[j ^ e]   (24 cndmask)
__device__ __forceinline__ void xperm8(float r[8], const int e) {
  const bool b0 = (e & 1) != 0, b1 = (e & 2) != 0, b2 = (e & 4) != 0;
  float t0[8], t1[8];
#pragma unroll
  for (int j = 0; j < 8; ++j) t0[j] = b0 ? r[j ^ 1] : r[j];
#pragma unroll
  for (int j = 0; j < 8; ++j) t1[j] = b1 ? t0[j ^ 2] : t0[j];
#pragma unroll
  for (int j = 0; j < 8; ++j) r[j] = b2 ? t1[j ^ 4] : t1[j];
}

// ---------- one tournament stage, XOR-relative storage ----------
// lane e stores ar[d] = A[e^d][e], ur[d] = U[e^d][e]. Pairs (i, i^M).
template<int M>
__device__ __forceinline__ void jstage(float ar[8], float ur[8], const int e) {
  constexpr int HB = (M >= 4) ? 4 : ((M >= 2) ? 2 : 1);  // highest bit of M
  constexpr int A1 = (M == 1) ? 2 : 1;                   // transversal masks
  constexpr int A2 = (M <= 3) ? 4 : 2;
  const bool low = (e & HB) == 0;      // is e the min of its pair
  // own diag = ar[0], own off-diag = ar[M] (both static!)
  float d_oth = sx<M>(ar[0]);
  float o_oth = sx<M>(ar[M]);
  float apq = 0.5f * (ar[M] + o_oth);  // symmetrized: both lanes identical
  float app = low ? ar[0] : d_oth;
  float aqq = low ? d_oth : ar[0];
  float taun = aqq - app;
  float den = fabsf(taun) + sqrtf(fmaf(taun, taun, 4.f * apq * apq)) + 1e-38f;
  float t = (2.f * apq) * copysignf(1.f, taun) * __builtin_amdgcn_rcpf(den);
  float c = rsqrtf(fmaf(t, t, 1.f));
  float s = t * c;                      // canonical (p=min, q=max) rotation
  // allgather canonical (c,s) of all 4 pairs into transversal slots (static idx)
  float cg[8], sg[8];
  cg[0] = c;  sg[0] = s;
  cg[A1] = sx<A1>(c);  sg[A1] = sx<A1>(s);
  cg[A2] = sx<A2>(c);  sg[A2] = sx<A2>(s);
  cg[A1 ^ A2] = sx<A2>(cg[A1]);  sg[A1 ^ A2] = sx<A2>(sg[A1]);
  // row update: A <- J^T A   (rel pair {d, d^M} uses slot rep(d))
  float an[8];
#pragma unroll
  for (int d = 0; d < 8; ++d) {
    constexpr int T0 = 0;
    const int rep = (d == T0 || d == A1 || d == A2 || d == (A1 ^ A2)) ? d : (d ^ M);
    const bool flip = (d & HB) != 0;       // abs row e^d is low iff low^flip
    float sD = sg[rep];
    float ss = (low != flip) ? -sD : sD;   // row_p gets -s, row_q gets +s
    an[d] = fmaf(cg[rep], ar[d], ss * ar[d ^ M]);
  }
  // col update: A <- A J ; U <- U J  (own pair's rotation; partner col via shfl)
  float scol = low ? -s : s;
  float aoth[8], uoth[8];
#pragma unroll
  for (int d = 0; d < 8; ++d) aoth[d] = sx<M>(an[d ^ M]);
#pragma unroll
  for (int d = 0; d < 8; ++d) uoth[d] = sx<M>(ur[d ^ M]);
#pragma unroll
  for (int d = 0; d < 8; ++d) ar[d] = fmaf(c, an[d], scol * aoth[d]);
#pragma unroll
  for (int d = 0; d < 8; ++d) ur[d] = fmaf(c, ur[d], scol * uoth[d]);
}

__device__ __forceinline__ void jacobi8rel(float ar[8], float ur[8], const int e) {
#pragma unroll
  for (int i = 0; i < 8; ++i) ur[i] = (i == 0) ? 1.f : 0.f;  // identity (relative)
#pragma unroll 1
  for (int sweep = 0; sweep < NSWEEP; ++sweep) {
    jstage<1>(ar, ur, e);
    jstage<2>(ar, ur, e);
    jstage<3>(ar, ur, e);
    jstage<4>(ar, ur, e);
    jstage<5>(ar, ur, e);
    jstage<6>(ar, ur, e);
    jstage<7>(ar, ur, e);
  }
}

// ---------------- Kernel B: eig pipeline, 1 wave = 8 batches ----------------
__global__ __launch_bounds__(64) void spd_eig8_kernel(
    const float* __restrict__ M1, const float* __restrict__ w2,
    const float* __restrict__ fc, float* __restrict__ out) {
  __shared__ __align__(16) float Wbuf[8 * WSTRIDE];
  __shared__ float lwbuf[64];
  __shared__ float w2s[64];
  __shared__ float fcs[128];
  const int tid = threadIdx.x;      // 0..63
  const int e = tid & 7;
  const int g = tid >> 3;           // 0..7, batch group
  const int b = blockIdx.x * 8 + g;
  w2s[tid] = w2[tid];
  fcs[tid] = fc[tid];
  fcs[tid + 64] = fc[tid + 64];

  float a[8], u[8], v[8], m2[8];
  float* Wg = &Wbuf[g * WSTRIDE];

  // load row e of symmetric M1 (= column e); coalesced 2KB per block
  const float4* m4 = (const float4*)(M1 + (size_t)b * 64 + e * 8);
  float4 v0 = m4[0], v1 = m4[1];
  a[0] = v0.x; a[1] = v0.y; a[2] = v0.z; a[3] = v0.w;
  a[4] = v1.x; a[5] = v1.y; a[6] = v1.z; a[7] = v1.w;
  __syncthreads();  // w2s/fcs ready (intra-wave: cheap)

  // ---- eig 1 ----
  xperm8(a, e);                 // absolute row -> relative column
  jacobi8rel(a, u, e);
  float lam = a[0];             // own eigenvalue (rel slot 0)
  float sw = sqrtf(fmaxf(lam, EPSV));
  xperm8(u, e);                 // u[i] = U[i][e] absolute
  // row e of V = U^T w2, scaled by sqrt(clamped eig)
#pragma unroll
  for (int j = 0; j < 8; ++j) v[j] = 0.f;
#pragma unroll
  for (int i = 0; i < 8; ++i)
#pragma unroll
    for (int j = 0; j < 8; ++j) v[j] = fmaf(u[i], w2s[i * 8 + j], v[j]);
#pragma unroll
  for (int j = 0; j < 8; ++j) Wg[e * 8 + j] = v[j] * sw;
  __syncthreads();
  // M2 column e: m2[i] = sum_k W[k][i] * W[k][e]
  {
    float wcol[8];
#pragma unroll
    for (int k = 0; k < 8; ++k) wcol[k] = Wg[k * 8 + e];
#pragma unroll
    for (int i = 0; i < 8; ++i) m2[i] = 0.f;
#pragma unroll
    for (int k = 0; k < 8; ++k) {
      float4 q0 = *(const float4*)&Wg[k * 8 + 0];
      float4 q1 = *(const float4*)&Wg[k * 8 + 4];
      m2[0] = fmaf(q0.x, wcol[k], m2[0]); m2[1] = fmaf(q0.y, wcol[k], m2[1]);
      m2[2] = fmaf(q0.z, wcol[k], m2[2]); m2[3] = fmaf(q0.w, wcol[k], m2[3]);
      m2[4] = fmaf(q1.x, wcol[k], m2[4]); m2[5] = fmaf(q1.y, wcol[k], m2[5]);
      m2[6] = fmaf(q1.z, wcol[k], m2[6]); m2[7] = fmaf(q1.w, wcol[k], m2[7]);
    }
  }
  __syncthreads();  // Wbuf reads done before reuse

  // ---- eig 2 + fused rec+logm ----
  xperm8(m2, e);
  jacobi8rel(m2, u, e);
  float lw = logf(fmaxf(m2[0], EPSV));
  xperm8(u, e);                 // absolute again
#pragma unroll
  for (int i = 0; i < 8; ++i) Wg[e * 8 + i] = u[i];
  lwbuf[g * 8 + e] = lw;
  __syncthreads();
  // feat column e: fcol[i] = sum_k lw_k * T[k][i] * T[k][e]
  {
    float mk[8];
#pragma unroll
    for (int k = 0; k < 8; ++k) mk[k] = lwbuf[g * 8 + k] * Wg[k * 8 + e];
    float fcol[8];
#pragma unroll
    for (int i = 0; i < 8; ++i) fcol[i] = 0.f;
#pragma unroll
    for (int k = 0; k < 8; ++k) {
      float4 q0 = *(const float4*)&Wg[k * 8 + 0];
      float4 q1 = *(const float4*)&Wg[k * 8 + 4];
      fcol[0] = fmaf(q0.x, mk[k], fcol[0]); fcol[1] = fmaf(q0.y, mk[k], fcol[1]);
      fcol[2] = fmaf(q0.z, mk[k], fcol[2]); fcol[3] = fmaf(q0.w, mk[k], fcol[3]);
      fcol[4] = fmaf(q1.x, mk[k], fcol[4]); fcol[5] = fmaf(q1.y, mk[k], fcol[5]);
      fcol[6] = fmaf(q1.z, mk[k], fcol[6]); fcol[7] = fmaf(q1.w, mk[k], fcol[7]);
    }
    float l0 = 0.f, l1 = 0.f;
    float* featg = out + 2 * (size_t)B_TOTAL + (size_t)b * 64;
#pragma unroll
    for (int i = 0; i < 8; ++i) {
      featg[i * 8 + e] = fcol[i];
      l0 = fmaf(fcol[i], fcs[(i * 8 + e) * 2 + 0], l0);
      l1 = fmaf(fcol[i], fcs[(i * 8 + e) * 2 + 1], l1);
    }
    l0 += sx<1>(l0); l0 += sx<2>(l0); l0 += sx<4>(l0);
    l1 += sx<1>(l1); l1 += sx<2>(l1); l1 += sx<4>(l1);
    float mx = fmaxf(l0, l1);
    float lse = mx + logf(expf(l0 - mx) + expf(l1 - mx));
    if (e < 2) out[(size_t)b * 2 + e] = (e ? l1 : l0) - lse;
  }
}

extern "C" void kernel_launch(void* const* d_in, const int* in_sizes, int n_in,
                              void* d_out, int out_size, void* d_ws, size_t ws_size,
                              hipStream_t stream) {
  const float* X  = (const float*)d_in[0];   // [8192,62,62]
  const float* w1 = (const float*)d_in[1];   // [62,8]
  const float* w2 = (const float*)d_in[2];   // [8,8]
  const float* fc = (const float*)d_in[3];   // [64,2]
  float* out = (float*)d_out;                // [8192*2] ++ [8192*64]
  float* M1 = (float*)d_ws;                  // 8192*64 floats = 2 MB

  bimap1_kernel<<<B_TOTAL, 64, 0, stream>>>(X, w1, M1);
  spd_eig8_kernel<<<B_TOTAL / 8, 64, 0, stream>>>(M1, w2, fc, out);
}